// Round 1
// baseline (743.069 us; speedup 1.0000x reference)
//
#include <hip/hip_runtime.h>

#define NN 6144
#define BND (NN*16)

typedef short short8 __attribute__((ext_vector_type(8)));
typedef float f32x4 __attribute__((ext_vector_type(4)));

__device__ __forceinline__ short f2bf(float f) {
    unsigned u = __builtin_bit_cast(unsigned, f);
    u = (u + 0x7FFFu + ((u >> 16) & 1u)) >> 16;   // RNE to bf16
    return (short)u;
}
__device__ __forceinline__ float bf2f(unsigned short s) {
    unsigned u = ((unsigned)s) << 16;
    return __builtin_bit_cast(float, u);
}

// ---------------- prep: transpose X [8,6144,16] fp32 -> Xt [128][6144] bf16 ----------------
__global__ void __launch_bounds__(256) prep_kernel(
    const float* __restrict__ xin, unsigned short* __restrict__ Xt)
{
    __shared__ unsigned short ldsT[16 * 64];
    const int b  = blockIdx.y;
    const int m0 = blockIdx.x * 64;
    const int t  = threadIdx.x;
    const int ml = t >> 2, dq = t & 3;
    float4 v = *(const float4*)(xin + (size_t)b * BND + (size_t)(m0 + ml) * 16 + dq * 4);
    ldsT[(dq * 4 + 0) * 64 + ml] = (unsigned short)f2bf(v.x);
    ldsT[(dq * 4 + 1) * 64 + ml] = (unsigned short)f2bf(v.y);
    ldsT[(dq * 4 + 2) * 64 + ml] = (unsigned short)f2bf(v.z);
    ldsT[(dq * 4 + 3) * 64 + ml] = (unsigned short)f2bf(v.w);
    __syncthreads();
    if (t < 128) {
        int d = t >> 3, j = t & 7;
        short8 s = *(const short8*)&ldsT[d * 64 + j * 8];
        *(short8*)(Xt + (size_t)(b * 16 + d) * NN + m0 + j * 8) = s;
    }
}

// ---------------- main: Ypart[seg][k][n][c] (bf16) = partial (sup_k @ X) ----------------
// Double-buffered (2x32KB LDS) 2-phase pipeline: stage tile t+1 with global_load_lds,
// compute tile t, then ONE counted drain (vmcnt(0)) + raw s_barrier per K-step.
// Loads stay in flight during the whole compute phase -> HBM duty ~100%
// (the old __syncthreads pair drained vmcnt before compute, idling HBM ~25%).
// Same XOR-swizzled source addressing so fragment ds_read_b128s stay ~2-way (free).

__device__ __forceinline__ void stage_tile(
    const float* __restrict__ Ab, const unsigned short* __restrict__ Xt,
    float* ldsA, unsigned short* ldsB, int n0, int k0, int tid)
{
    // ---- stage A: 16 KB fp32, coalesced, src-XOR-swizzled ----
#pragma unroll
    for (int i = 0; i < 4; ++i) {
        int p = i * 256 + tid;
        int r = p >> 4, cs = p & 15;
        int cch = cs ^ (r & 7);
        const float* src = Ab + (size_t)(n0 + r) * NN + k0 + cch * 4;
        __builtin_amdgcn_global_load_lds(
            (const __attribute__((address_space(1))) unsigned int*)src,
            (__attribute__((address_space(3))) unsigned int*)((char*)ldsA + p * 16), 16, 0, 0);
    }
    // ---- stage B: 16 KB bf16 from Xt (L2), coalesced, src-XOR-swizzled ----
#pragma unroll
    for (int i = 0; i < 4; ++i) {
        int p = i * 256 + tid;
        int c = p >> 3, hs = p & 7;
        int h = hs ^ (c & 7);
        const unsigned short* src = Xt + (size_t)c * NN + k0 + h * 8;
        __builtin_amdgcn_global_load_lds(
            (const __attribute__((address_space(1))) unsigned int*)src,
            (__attribute__((address_space(3))) unsigned int*)((char*)ldsB + p * 16), 16, 0, 0);
    }
}

__device__ __forceinline__ void compute_tile(
    const float* ldsA, const unsigned short* ldsB,
    int w, int q, int col, f32x4* acc)
{
    const int r = w * 16 + col;   // wave w owns rows [w*16, w*16+16)
#pragma unroll
    for (int kc = 0; kc < 2; ++kc) {
        int c0 = kc * 8 + q * 2;
        float4 a0 = *(const float4*)&ldsA[(r * 16 + ((c0    ) ^ (r & 7))) * 4];
        float4 a1 = *(const float4*)&ldsA[(r * 16 + ((c0 + 1) ^ (r & 7))) * 4];
        short8 af;
        af[0] = f2bf(a0.x); af[1] = f2bf(a0.y); af[2] = f2bf(a0.z); af[3] = f2bf(a0.w);
        af[4] = f2bf(a1.x); af[5] = f2bf(a1.y); af[6] = f2bf(a1.z); af[7] = f2bf(a1.w);
#pragma unroll
        for (int cc = 0; cc < 8; ++cc) {
            int c = cc * 16 + col;
            short8 bf = *(const short8*)&ldsB[(c * 8 + ((kc * 4 + q) ^ (c & 7))) * 8];
            acc[cc] = __builtin_amdgcn_mfma_f32_16x16x32_bf16(af, bf, acc[cc], 0, 0, 0);
        }
    }
}

__global__ void __launch_bounds__(256, 2) gemm_kernel(
    const float* __restrict__ sup, const unsigned short* __restrict__ Xt,
    unsigned short* __restrict__ Yp)
{
    __shared__ float ldsram[16384];                       // 64 KB: two 32 KB buffers
    float* A0 = ldsram;                                   // buf0: A 16 KB
    unsigned short* B0 = (unsigned short*)(ldsram + 4096);//       B 16 KB
    float* A1 = ldsram + 8192;                            // buf1
    unsigned short* B1 = (unsigned short*)(ldsram + 12288);

    const int tid = threadIdx.x;
    const int w = tid >> 6, L = tid & 63, q = L >> 4, col = L & 15;
    const int n0  = blockIdx.x * 64;
    const int k   = blockIdx.y;
    const int seg = blockIdx.z;
    const float* Ab = sup + (size_t)k * NN * NN;
    const int kbase = seg * 3072;

    f32x4 acc[8];
#pragma unroll
    for (int i = 0; i < 8; ++i) acc[i] = (f32x4)0.0f;

    // prologue: tile 0 into buf0
    stage_tile(Ab, Xt, A0, B0, n0, kbase, tid);
    asm volatile("s_waitcnt vmcnt(0)" ::: "memory");
    __builtin_amdgcn_s_barrier();

#pragma unroll 1
    for (int it = 0; it < 48; it += 2) {
        // even half: prefetch tile it+1 into buf1, compute buf0
        stage_tile(Ab, Xt, A1, B1, n0, kbase + (it + 1) * 64, tid);
        __builtin_amdgcn_sched_barrier(0);
        compute_tile(A0, B0, w, q, col, acc);
        asm volatile("s_waitcnt vmcnt(0)" ::: "memory");
        __builtin_amdgcn_s_barrier();
        // odd half: prefetch tile it+2 into buf0 (if any), compute buf1
        if (it + 2 < 48) {
            stage_tile(Ab, Xt, A0, B0, n0, kbase + (it + 2) * 64, tid);
            __builtin_amdgcn_sched_barrier(0);
            compute_tile(A1, B1, w, q, col, acc);
            asm volatile("s_waitcnt vmcnt(0)" ::: "memory");
            __builtin_amdgcn_s_barrier();
        } else {
            compute_tile(A1, B1, w, q, col, acc);
        }
    }

    // ---- epilogue: assemble in LDS (each wave its own 8 KB region in buf0; the
    // last-computed tile lives in buf1, so no barrier needed), bf16 coalesced store ----
    float* stg = ldsram + w * 2048;    // [16 rows][128 c]
#pragma unroll
    for (int cc = 0; cc < 8; ++cc)
#pragma unroll
        for (int rr = 0; rr < 4; ++rr)
            stg[(q * 4 + rr) * 128 + cc * 16 + col] = acc[cc][rr];  // C/D: col=lane&15, row=q*4+reg

    unsigned short* ypb = Yp + ((size_t)(seg * 3 + k) * NN + n0 + w * 16) * 128;
#pragma unroll
    for (int u = 0; u < 8; ++u) {
        int idx = u * 256 + L * 4;                // conflict-free float4 LDS read
        float4 v = *(const float4*)&stg[idx];
        unsigned h0 = (unsigned short)f2bf(v.x) | ((unsigned)(unsigned short)f2bf(v.y) << 16);
        unsigned h1 = (unsigned short)f2bf(v.z) | ((unsigned)(unsigned short)f2bf(v.w) << 16);
        uint2 pk; pk.x = h0; pk.y = h1;
        *(uint2*)(ypb + idx) = pk;                // rr = idx>>7, c = idx&127 folded linearly
    }
}

// ---------------- stage 2: out[b,n,o] = bias[o] + sum_{s,k,d} Yp*W' + identity ----------------
__global__ void __launch_bounds__(256) out_kernel(
    const unsigned short* __restrict__ Yp, const float* __restrict__ xin,
    const float* __restrict__ W, const float* __restrict__ bias, float* __restrict__ out)
{
    const int o   = threadIdx.x & 63;
    const int wid = blockIdx.x * 4 + (threadIdx.x >> 6);  // 2048 waves

    float wreg[48];                       // wreg[k*16+d] = W[o][d*3+k]
#pragma unroll
    for (int d = 0; d < 16; ++d)
#pragma unroll
        for (int kk = 0; kk < 3; ++kk)
            wreg[kk * 16 + d] = W[o * 48 + d * 3 + kk];
    float wsum[16];                       // identity term: sum_k wreg[k*16+d]
#pragma unroll
    for (int d = 0; d < 16; ++d) wsum[d] = wreg[d] + wreg[16 + d] + wreg[32 + d];
    const float bv = bias[o];

    for (int ii = 0; ii < 24; ++ii) {
        int p = wid * 24 + ii;            // p in [0, 49152)
        int b = p / NN;
        int n = p - b * NN;
        float acc = bv;
        const float* xp = xin + (size_t)b * BND + (size_t)n * 16;
#pragma unroll
        for (int d4 = 0; d4 < 4; ++d4) {
            float4 x4 = *(const float4*)(xp + d4 * 4);
            acc += x4.x * wsum[d4 * 4] + x4.y * wsum[d4 * 4 + 1]
                 + x4.z * wsum[d4 * 4 + 2] + x4.w * wsum[d4 * 4 + 3];
        }
#pragma unroll
        for (int s = 0; s < 2; ++s)
#pragma unroll
            for (int kk = 0; kk < 3; ++kk) {
                const unsigned short* yp = Yp + ((size_t)(s * 3 + kk) * NN + n) * 128 + b * 16;
                short8 y0 = *(const short8*)yp;
                short8 y1 = *(const short8*)(yp + 8);
#pragma unroll
                for (int j = 0; j < 8; ++j) {
                    acc += bf2f((unsigned short)y0[j]) * wreg[kk * 16 + j];
                    acc += bf2f((unsigned short)y1[j]) * wreg[kk * 16 + 8 + j];
                }
            }
        out[(size_t)p * 64 + o] = acc;
    }
}

extern "C" void kernel_launch(void* const* d_in, const int* in_sizes, int n_in,
                              void* d_out, int out_size, void* d_ws, size_t ws_size,
                              hipStream_t stream) {
    const float* xin  = (const float*)d_in[0];  // [8,6144,16]
    const float* sup  = (const float*)d_in[1];  // [3,6144,6144]
    const float* W    = (const float*)d_in[2];  // [64,48]
    const float* bias = (const float*)d_in[3];  // [64]
    float* out = (float*)d_out;                 // [8,6144,64]

    char* ws = (char*)d_ws;
    unsigned short* Xt = (unsigned short*)ws;        // 128*6144*2B = 1,572,864
    unsigned short* Yp = (unsigned short*)(ws + 1572864); // 2*3*6144*128*2B = 9,437,184

    prep_kernel<<<dim3(96, 8), 256, 0, stream>>>(xin, Xt);
    gemm_kernel<<<dim3(96, 3, 2), 256, 0, stream>>>(sup, Xt, Yp);
    out_kernel<<<512, 256, 0, stream>>>(Yp, xin, W, bias, out);
}

// Round 2
// 720.500 us; speedup vs baseline: 1.0313x; 1.0313x over previous
//
#include <hip/hip_runtime.h>

#define NN 6144
#define BND (NN*16)

typedef short short8 __attribute__((ext_vector_type(8)));
typedef float f32x4 __attribute__((ext_vector_type(4)));

__device__ __forceinline__ short f2bf(float f) {
    unsigned u = __builtin_bit_cast(unsigned, f);
    u = (u + 0x7FFFu + ((u >> 16) & 1u)) >> 16;   // RNE to bf16
    return (short)u;
}
__device__ __forceinline__ float bf2f(unsigned short s) {
    unsigned u = ((unsigned)s) << 16;
    return __builtin_bit_cast(float, u);
}

// ---------------- prep: transpose X [8,6144,16] fp32 -> Xt [128][6144] bf16 ----------------
__global__ void __launch_bounds__(256) prep_kernel(
    const float* __restrict__ xin, unsigned short* __restrict__ Xt)
{
    __shared__ unsigned short ldsT[16 * 64];
    const int b  = blockIdx.y;
    const int m0 = blockIdx.x * 64;
    const int t  = threadIdx.x;
    const int ml = t >> 2, dq = t & 3;
    float4 v = *(const float4*)(xin + (size_t)b * BND + (size_t)(m0 + ml) * 16 + dq * 4);
    ldsT[(dq * 4 + 0) * 64 + ml] = (unsigned short)f2bf(v.x);
    ldsT[(dq * 4 + 1) * 64 + ml] = (unsigned short)f2bf(v.y);
    ldsT[(dq * 4 + 2) * 64 + ml] = (unsigned short)f2bf(v.z);
    ldsT[(dq * 4 + 3) * 64 + ml] = (unsigned short)f2bf(v.w);
    __syncthreads();
    if (t < 128) {
        int d = t >> 3, j = t & 7;
        short8 s = *(const short8*)&ldsT[d * 64 + j * 8];
        *(short8*)(Xt + (size_t)(b * 16 + d) * NN + m0 + j * 8) = s;
    }
}

// ---------------- main: Ypart[seg][k][n][c] (bf16) = partial (sup_k @ X) ----------------
// 3-buffer ring, BK=32, depth-2 prefetch with COUNTED vmcnt (never 0 in the loop).
// Per K-step: wait vmcnt(4) [tile t+1's 4 loads stay in flight, tile t complete],
// one s_barrier, stage tile t+2, compute tile t. 48 KB LDS -> 3 blocks/CU, all
// 576 blocks co-resident (no tail), so cross-block overlap is preserved AND each
// block keeps 8 loads/thread in flight through its compute phase.

__device__ __forceinline__ void stage_tile32(
    const float* __restrict__ Ab, const unsigned short* __restrict__ Xt,
    float* ldsA, unsigned short* ldsB, int n0, int k0, int tid)
{
    // ---- stage A: 8 KB fp32 (64 rows x 32 k), coalesced, src-XOR-swizzled ----
#pragma unroll
    for (int i = 0; i < 2; ++i) {
        int p = i * 256 + tid;
        int r = p >> 3, cs = p & 7;
        int cch = cs ^ (r & 7);
        const float* src = Ab + (size_t)(n0 + r) * NN + k0 + cch * 4;
        __builtin_amdgcn_global_load_lds(
            (const __attribute__((address_space(1))) unsigned int*)src,
            (__attribute__((address_space(3))) unsigned int*)((char*)ldsA + p * 16), 16, 0, 0);
    }
    // ---- stage B: 8 KB bf16 (128 cols x 32 k) from Xt (L2), src-XOR-swizzled ----
#pragma unroll
    for (int i = 0; i < 2; ++i) {
        int p = i * 256 + tid;
        int c = p >> 2, hs = p & 3;
        int h = hs ^ (c & 3);
        const unsigned short* src = Xt + (size_t)c * NN + k0 + h * 8;
        __builtin_amdgcn_global_load_lds(
            (const __attribute__((address_space(1))) unsigned int*)src,
            (__attribute__((address_space(3))) unsigned int*)((char*)ldsB + p * 16), 16, 0, 0);
    }
}

__device__ __forceinline__ void compute_tile32(
    const float* ldsA, const unsigned short* ldsB,
    int w, int q, int col, f32x4* acc)
{
    const int r = w * 16 + col;   // wave w owns rows [w*16, w*16+16)
    // A frag: 8 consecutive fp32 at row r, k = q*8..q*8+7 -> chunks 2q, 2q+1 (XOR-swz)
    float4 a0 = *(const float4*)&ldsA[(r * 8 + ((2 * q    ) ^ (r & 7))) * 4];
    float4 a1 = *(const float4*)&ldsA[(r * 8 + ((2 * q + 1) ^ (r & 7))) * 4];
    short8 af;
    af[0] = f2bf(a0.x); af[1] = f2bf(a0.y); af[2] = f2bf(a0.z); af[3] = f2bf(a0.w);
    af[4] = f2bf(a1.x); af[5] = f2bf(a1.y); af[6] = f2bf(a1.z); af[7] = f2bf(a1.w);
#pragma unroll
    for (int cc = 0; cc < 8; ++cc) {
        int c = cc * 16 + col;
        short8 bf = *(const short8*)&ldsB[(c * 4 + (q ^ (c & 3))) * 8];
        acc[cc] = __builtin_amdgcn_mfma_f32_16x16x32_bf16(af, bf, acc[cc], 0, 0, 0);
    }
}

__global__ void __launch_bounds__(256, 4) gemm_kernel(
    const float* __restrict__ sup, const unsigned short* __restrict__ Xt,
    unsigned short* __restrict__ Yp)
{
    __shared__ float ldsram[12288];   // 48 KB: 3 buffers x (A 8 KB + B 8 KB)

    const int tid = threadIdx.x;
    const int w = tid >> 6, L = tid & 63, q = L >> 4, col = L & 15;
    const int n0  = blockIdx.x * 64;
    const int k   = blockIdx.y;
    const int seg = blockIdx.z;
    const float* Ab = sup + (size_t)k * NN * NN;
    const int kbase = seg * 3072;

    f32x4 acc[8];
#pragma unroll
    for (int i = 0; i < 8; ++i) acc[i] = (f32x4)0.0f;

    // prologue: tiles 0,1 into buffers 0,1
    stage_tile32(Ab, Xt, ldsram,        (unsigned short*)(ldsram + 2048),        n0, kbase,      tid);
    stage_tile32(Ab, Xt, ldsram + 4096, (unsigned short*)(ldsram + 4096 + 2048), n0, kbase + 32, tid);

    int cur = 0;   // buffer holding tile t
#pragma unroll 1
    for (int t = 0; t < 95; ++t) {
        // tile t was issued two phases ago; tile t+1's 4 loads may remain in flight
        asm volatile("s_waitcnt vmcnt(4)" ::: "memory");
        __builtin_amdgcn_s_barrier();
        __builtin_amdgcn_sched_barrier(0);
        int sd = cur + 2; if (sd >= 3) sd -= 3;          // dest buffer for tile t+2
        if (t + 2 < 96) {
            float* dA = ldsram + sd * 4096;
            stage_tile32(Ab, Xt, dA, (unsigned short*)(dA + 2048),
                         n0, kbase + (t + 2) * 32, tid);
        }
        __builtin_amdgcn_sched_barrier(0);
        const float* cA = ldsram + cur * 4096;
        compute_tile32(cA, (const unsigned short*)(cA + 2048), w, q, col, acc);
        cur = (cur == 2) ? 0 : cur + 1;
    }
    // peeled last step: only tile 95's loads remain -> full drain once
    asm volatile("s_waitcnt vmcnt(0)" ::: "memory");
    __builtin_amdgcn_s_barrier();
    __builtin_amdgcn_sched_barrier(0);
    {
        const float* cA = ldsram + cur * 4096;            // cur == 95 % 3 == 2
        compute_tile32(cA, (const unsigned short*)(cA + 2048), w, q, col, acc);
    }

    // ---- epilogue: stage in buf0+buf1 (floats 0..8191) — disjoint from buf2 which the
    // last compute read, and each wave reads/writes only its own 8 KB region ----
    float* stg = ldsram + w * 2048;    // [16 rows][128 c]
#pragma unroll
    for (int cc = 0; cc < 8; ++cc)
#pragma unroll
        for (int rr = 0; rr < 4; ++rr)
            stg[(q * 4 + rr) * 128 + cc * 16 + col] = acc[cc][rr];  // C/D: col=lane&15, row=q*4+reg

    unsigned short* ypb = Yp + ((size_t)(seg * 3 + k) * NN + n0 + w * 16) * 128;
#pragma unroll
    for (int u = 0; u < 8; ++u) {
        int idx = u * 256 + L * 4;                // conflict-free float4 LDS read
        float4 v = *(const float4*)&stg[idx];
        unsigned h0 = (unsigned short)f2bf(v.x) | ((unsigned)(unsigned short)f2bf(v.y) << 16);
        unsigned h1 = (unsigned short)f2bf(v.z) | ((unsigned)(unsigned short)f2bf(v.w) << 16);
        uint2 pk; pk.x = h0; pk.y = h1;
        *(uint2*)(ypb + idx) = pk;                // rr = idx>>7, c = idx&127 folded linearly
    }
}

// ---------------- stage 2: out[b,n,o] = bias[o] + sum_{s,k,d} Yp*W' + identity ----------------
__global__ void __launch_bounds__(256) out_kernel(
    const unsigned short* __restrict__ Yp, const float* __restrict__ xin,
    const float* __restrict__ W, const float* __restrict__ bias, float* __restrict__ out)
{
    const int o   = threadIdx.x & 63;
    const int wid = blockIdx.x * 4 + (threadIdx.x >> 6);  // 2048 waves

    float wreg[48];                       // wreg[k*16+d] = W[o][d*3+k]
#pragma unroll
    for (int d = 0; d < 16; ++d)
#pragma unroll
        for (int kk = 0; kk < 3; ++kk)
            wreg[kk * 16 + d] = W[o * 48 + d * 3 + kk];
    float wsum[16];                       // identity term: sum_k wreg[k*16+d]
#pragma unroll
    for (int d = 0; d < 16; ++d) wsum[d] = wreg[d] + wreg[16 + d] + wreg[32 + d];
    const float bv = bias[o];

    for (int ii = 0; ii < 24; ++ii) {
        int p = wid * 24 + ii;            // p in [0, 49152)
        int b = p / NN;
        int n = p - b * NN;
        float acc = bv;
        const float* xp = xin + (size_t)b * BND + (size_t)n * 16;
#pragma unroll
        for (int d4 = 0; d4 < 4; ++d4) {
            float4 x4 = *(const float4*)(xp + d4 * 4);
            acc += x4.x * wsum[d4 * 4] + x4.y * wsum[d4 * 4 + 1]
                 + x4.z * wsum[d4 * 4 + 2] + x4.w * wsum[d4 * 4 + 3];
        }
#pragma unroll
        for (int s = 0; s < 2; ++s)
#pragma unroll
            for (int kk = 0; kk < 3; ++kk) {
                const unsigned short* yp = Yp + ((size_t)(s * 3 + kk) * NN + n) * 128 + b * 16;
                short8 y0 = *(const short8*)yp;
                short8 y1 = *(const short8*)(yp + 8);
#pragma unroll
                for (int j = 0; j < 8; ++j) {
                    acc += bf2f((unsigned short)y0[j]) * wreg[kk * 16 + j];
                    acc += bf2f((unsigned short)y1[j]) * wreg[kk * 16 + 8 + j];
                }
            }
        out[(size_t)p * 64 + o] = acc;
    }
}

extern "C" void kernel_launch(void* const* d_in, const int* in_sizes, int n_in,
                              void* d_out, int out_size, void* d_ws, size_t ws_size,
                              hipStream_t stream) {
    const float* xin  = (const float*)d_in[0];  // [8,6144,16]
    const float* sup  = (const float*)d_in[1];  // [3,6144,6144]
    const float* W    = (const float*)d_in[2];  // [64,48]
    const float* bias = (const float*)d_in[3];  // [64]
    float* out = (float*)d_out;                 // [8,6144,64]

    char* ws = (char*)d_ws;
    unsigned short* Xt = (unsigned short*)ws;        // 128*6144*2B = 1,572,864
    unsigned short* Yp = (unsigned short*)(ws + 1572864); // 2*3*6144*128*2B = 9,437,184

    prep_kernel<<<dim3(96, 8), 256, 0, stream>>>(xin, Xt);
    gemm_kernel<<<dim3(96, 3, 2), 256, 0, stream>>>(sup, Xt, Yp);
    out_kernel<<<512, 256, 0, stream>>>(Yp, xin, W, bias, out);
}